// Round 11
// baseline (164.604 us; speedup 1.0000x reference)
//
#include <hip/hip_runtime.h>

#define B_    64
#define HW_   196
#define HWP_  224
#define D_    768
#define E_    256
#define C_    10
#define MP_   (B_*HWP_)   // 14336 padded rows
#define K3K_  (E_*D_)     // 196608 = e*d flattened

typedef __bf16 bf16x8 __attribute__((ext_vector_type(8)));
typedef __bf16 bf16x4 __attribute__((ext_vector_type(4)));
typedef __bf16 bf16x2 __attribute__((ext_vector_type(2)));
typedef float  f32x4  __attribute__((ext_vector_type(4)));

// async global->LDS, 16B per lane; LDS dest is wave-uniform base + lane*16
__device__ __forceinline__ void gld_lds16(const void* g, void* l) {
  __builtin_amdgcn_global_load_lds((const __attribute__((address_space(1))) void*)g,
                                   (__attribute__((address_space(3))) void*)l, 16, 0, 0);
}

// ---------------- K0prep: {ag_w -> bf16 hi/lo} + {lm_w -> w2[c][e][d] bf16} --------
__global__ __launch_bounds__(256) void k0_prep(const float* __restrict__ w,
                                               __bf16* __restrict__ whi,
                                               __bf16* __restrict__ wlo,
                                               const float* __restrict__ lmw,
                                               __bf16* __restrict__ w2) {
  int bid = blockIdx.x;
  if (bid < 192) {
    size_t i4 = ((size_t)bid * 256 + threadIdx.x) * 4;
    float4 v = *(const float4*)&w[i4];
    float vv[4] = {v.x, v.y, v.z, v.w};
    bf16x4 h, l;
#pragma unroll
    for (int j = 0; j < 4; j++) {
      __bf16 hj = (__bf16)vv[j];
      float r = vv[j] - (float)hj;
      h[j] = hj;
      l[j] = (__bf16)r;
    }
    *(bf16x4*)&whi[i4] = h;
    *(bf16x4*)&wlo[i4] = l;
  } else {
    // 10*K3K_ elems; linear out index == i4; reads coalesced (d contiguous)
    size_t i4 = ((size_t)(bid - 192) * 256 + threadIdx.x) * 4;
    int c = (int)(i4 / K3K_);
    int rem = (int)(i4 - (size_t)c * K3K_);
    int e = rem / D_;
    int d = rem - e * D_;
    float4 v = *(const float4*)&lmw[((size_t)e * C_ + c) * D_ + d];
    bf16x4 o;
    o[0] = (__bf16)v.x; o[1] = (__bf16)v.y; o[2] = (__bf16)v.z; o[3] = (__bf16)v.w;
    *(bf16x4*)&w2[i4] = o;
  }
}

// ---------------- K1: sign GEMM (R8 version: depth-2, drain-free) -----------
__global__ __launch_bounds__(256) void k1_signs(const float* __restrict__ x,
                                                const __bf16* __restrict__ whi,
                                                const __bf16* __restrict__ wlo,
                                                const float* __restrict__ bias,
                                                __bf16* __restrict__ st) {
  __shared__ __align__(16) char smem[118784];  // B 3x32KB = 96KB | A 2x10KB = 20KB
  const int m0 = blockIdx.x * 64;
  const int tid = threadIdx.x;
  const int wave = tid >> 6, lane = tid & 63;
  const int wn = wave * 64;                    // e-offset of this wave
  const int q = lane >> 4, l15 = lane & 15;
  const int swq = (q ^ ((l15 >> 1) & 3)) * 8;  // B read-side swizzled k-col

  const int ar = tid >> 2, ac = (tid & 3) * 8;
  const int am = m0 + ar;
  const int ab = am / HWP_;
  const int ahp = am - ab * HWP_;
  const bool avalid = (ahp < HW_);
  const float* aptr = &x[((size_t)ab * HW_ + (avalid ? ahp : 0)) * D_ + ac];

  const int swB = ((tid & 3) ^ ((tid >> 3) & 3)) * 8;   // source-side swizzle
  const size_t offB = (size_t)(tid >> 2) * D_ + swB;

  f32x4 acc[4][4] = {};
  float4 aX0, aX1, aY0, aY1;

#define K1_LOADA(r0, r1, kk) do { \
    r0 = *(const float4*)&aptr[(kk)]; \
    r1 = *(const float4*)&aptr[(kk) + 4]; \
  } while (0)

#define K1_CONV(bufA, r0, r1) do { \
    __bf16* AhW = (__bf16*)(smem + 98304 + (bufA) * 10240); \
    __bf16* AlW = AhW + 2560; \
    float va[8] = {r0.x, r0.y, r0.z, r0.w, r1.x, r1.y, r1.z, r1.w}; \
    bf16x8 hh, ll; \
    _Pragma("unroll") \
    for (int j = 0; j < 8; j++) { \
      float vj = avalid ? va[j] : 0.0f; \
      __bf16 hj = (__bf16)vj; float rr = vj - (float)hj; \
      hh[j] = hj; ll[j] = (__bf16)rr; \
    } \
    *(bf16x8*)&AhW[ar * 40 + ac] = hh; \
    *(bf16x8*)&AlW[ar * 40 + ac] = ll; \
  } while (0)

#define K1_DMAB(buf3, kk) do { \
    char* bb = smem + (buf3) * 32768; \
    _Pragma("unroll") \
    for (int c = 0; c < 4; c++) { \
      gld_lds16(&whi[offB + (size_t)c * 64 * D_ + (kk)], bb + c * 4096 + wave * 1024); \
      gld_lds16(&wlo[offB + (size_t)c * 64 * D_ + (kk)], bb + 16384 + c * 4096 + wave * 1024); \
    } \
  } while (0)

#define K1_COMPUTE(buf3, bufA) do { \
    const __bf16* BhL = (const __bf16*)(smem + (buf3) * 32768); \
    const __bf16* BlL = BhL + 8192; \
    const __bf16* AhL = (const __bf16*)(smem + 98304 + (bufA) * 10240); \
    const __bf16* AlL = AhL + 2560; \
    bf16x8 ah[4], al[4], bh[4], bl[4]; \
    _Pragma("unroll") \
    for (int t = 0; t < 4; t++) { \
      int ra = (t * 16 + l15) * 40 + q * 8; \
      int rb = (wn + t * 16 + l15) * 32 + swq; \
      ah[t] = *(const bf16x8*)&AhL[ra]; \
      al[t] = *(const bf16x8*)&AlL[ra]; \
      bh[t] = *(const bf16x8*)&BhL[rb]; \
      bl[t] = *(const bf16x8*)&BlL[rb]; \
    } \
    __builtin_amdgcn_s_setprio(1); \
    _Pragma("unroll") \
    for (int mt = 0; mt < 4; mt++) \
      _Pragma("unroll") \
      for (int nt = 0; nt < 4; nt++) { \
        acc[mt][nt] = __builtin_amdgcn_mfma_f32_16x16x32_bf16(ah[mt], bh[nt], acc[mt][nt], 0, 0, 0); \
        acc[mt][nt] = __builtin_amdgcn_mfma_f32_16x16x32_bf16(al[mt], bh[nt], acc[mt][nt], 0, 0, 0); \
        acc[mt][nt] = __builtin_amdgcn_mfma_f32_16x16x32_bf16(ah[mt], bl[nt], acc[mt][nt], 0, 0, 0); \
      } \
    __builtin_amdgcn_s_setprio(0); \
  } while (0)

#define K1_BAR() do { \
    asm volatile("s_waitcnt lgkmcnt(0)" ::: "memory"); \
    __builtin_amdgcn_s_barrier(); \
    __builtin_amdgcn_sched_barrier(0); \
  } while (0)

  K1_DMAB(0, 0);
  __builtin_amdgcn_sched_barrier(0);
  K1_LOADA(aX0, aX1, 0);
  __builtin_amdgcn_sched_barrier(0);
  K1_DMAB(1, 32);
  __builtin_amdgcn_sched_barrier(0);
  K1_LOADA(aY0, aY1, 32);
  K1_CONV(0, aX0, aX1);
  K1_BAR();

#pragma unroll
  for (int t = 0; t < 22; ++t) {
    K1_DMAB((t + 2) % 3, (t + 2) * 32);
    __builtin_amdgcn_sched_barrier(0);
    if ((t & 1) == 0) K1_LOADA(aX0, aX1, (t + 2) * 32);
    else              K1_LOADA(aY0, aY1, (t + 2) * 32);
    K1_COMPUTE(t % 3, t & 1);
    if ((t & 1) == 0) K1_CONV(1, aY0, aY1);
    else              K1_CONV(0, aX0, aX1);
    K1_BAR();
  }
  K1_COMPUTE(22 % 3, 0);
  K1_CONV(1, aY0, aY1);
  K1_BAR();
  K1_COMPUTE(23 % 3, 1);
  K1_BAR();

#undef K1_LOADA
#undef K1_CONV
#undef K1_DMAB
#undef K1_COMPUTE
#undef K1_BAR

  __bf16* Sload = (__bf16*)smem;         // [256][72] = 36 KB
#pragma unroll
  for (int mt = 0; mt < 4; mt++)
#pragma unroll
    for (int nt = 0; nt < 4; nt++) {
      int e = wn + nt * 16 + l15;
      float bv = bias[e];
      bf16x4 o;
#pragma unroll
      for (int r = 0; r < 4; r++) {
        int m = m0 + mt * 16 + q * 4 + r;
        int b = m / HWP_;
        int hp = m - b * HWP_;
        float v = acc[mt][nt][r] + bv;
        o[r] = (hp < HW_ && v > 0.0f) ? (__bf16)1.0f : (__bf16)0.0f;
      }
      *(bf16x4*)&Sload[e * 72 + mt * 16 + q * 4] = o;
    }
  __syncthreads();
#pragma unroll
  for (int it = 0; it < 16; it++) {
    int e = (tid >> 4) + it * 16;
    int m4 = (tid & 15) * 4;
    bf16x4 v = *(const bf16x4*)&Sload[e * 72 + m4];
    int mabs = m0 + m4;
    int b = mabs / HWP_;
    int hp = mabs - b * HWP_;
    *(bf16x4*)&st[((size_t)b * E_ + e) * HWP_ + hp] = v;
  }
}

// ---------------- K2f: G = S^T·X (256e x 96d) fused with final contraction --------
// Grid 512 = 8 d-slices x 64 b; d0g = blockIdx&7 -> all 64 blocks sharing one
// 491 KB w2 slice land on ONE XCD (L2-resident; fixes R9's 503 MB amplification).
// Epilogue: G(f32 acc) -> bf16 LDS two-pass, 8-elem chunked contraction vs bf16
// w2[c][e][d] (16B-aligned bf16x8 reads, no spill arrays), butterfly reduce ->
// 10 floats/block. g tensor NEVER materialized.
__global__ __launch_bounds__(512) void k2_fused(const __bf16* __restrict__ st,
                                                const float* __restrict__ x,
                                                const __bf16* __restrict__ w2,
                                                float* __restrict__ part) {
  __shared__ __align__(16) char smem2[48128];        // As 32KB | Bs 15.4KB ; Gl 26.6KB
  __bf16* As = (__bf16*)smem2;                       // [2][256*32]
  __bf16* Bs = (__bf16*)(smem2 + 32768);             // [2][96*40]
  const int f = blockIdx.x;                // 0..511
  const int d0g = f & 7;                   // d-slice -> XCD class
  const int b   = f >> 3;                  // batch
  const int dbase = d0g * 96;
  const int tid = threadIdx.x;
  const int wave = tid >> 6, lane = tid & 63;
  const int WE = (wave & 3) * 64;          // e-offset
  const int WD = (wave >> 2) * 48;         // d-offset within 96
  const int q = lane >> 4, l15 = lane & 15;
  const int ar = tid >> 2, ac = (tid & 3) * 8;
  const int ldA = wave * 512;
  // B staging: thread owns 3 d x 2 hp
  const int dg = tid & 31;                 // d = dg*3
  const int kp = tid >> 5;                 // hp pair = 2*kp
  f32x4 acc[4][3] = {};

  const __bf16* gA = &st[((size_t)b * E_ + ar) * HWP_ + ac];
  float b00, b01, b02, b10, b11, b12;

#define K2_STAGEA(buf, kk) do { \
    gld_lds16(gA + (kk),                       &As[(buf) * 8192 + ldA]); \
    gld_lds16(gA + (size_t)128 * HWP_ + (kk),  &As[(buf) * 8192 + 4096 + ldA]); \
  } while (0)

#define K2_LOADB(kk) do { \
    int hp0 = (kk) + 2 * kp; \
    const float* bsrc = &x[((size_t)b * HW_ + hp0) * D_ + dbase + dg * 3]; \
    bool v0 = (hp0 < HW_), v1 = (hp0 + 1 < HW_); \
    b00 = v0 ? bsrc[0] : 0.f; b01 = v0 ? bsrc[1] : 0.f; b02 = v0 ? bsrc[2] : 0.f; \
    b10 = v1 ? bsrc[D_] : 0.f; b11 = v1 ? bsrc[D_ + 1] : 0.f; b12 = v1 ? bsrc[D_ + 2] : 0.f; \
  } while (0)

#define K2_WRITEB(buf) do { \
    float r0j[3] = {b00, b01, b02}; \
    float r1j[3] = {b10, b11, b12}; \
    _Pragma("unroll") \
    for (int j = 0; j < 3; j++) { \
      bf16x2 o; \
      o[0] = (__bf16)r0j[j]; o[1] = (__bf16)r1j[j]; \
      *(bf16x2*)&Bs[(buf) * 3840 + (dg * 3 + j) * 40 + 2 * kp] = o; \
    } \
  } while (0)

  K2_STAGEA(0, 0);
  K2_LOADB(0);
  K2_WRITEB(0);
  __syncthreads();

  int cur = 0;
  for (int k0 = 0; k0 < HWP_; k0 += 32) {
    const bool have = (k0 + 32 < HWP_);
    if (have) {
      K2_STAGEA(cur ^ 1, k0 + 32);
      K2_LOADB(k0 + 32);
    }
    bf16x8 af[4], bfr[3];
#pragma unroll
    for (int t = 0; t < 4; t++)
      af[t] = *(const bf16x8*)&As[cur * 8192 + (WE + t * 16 + l15) * 32 + q * 8];
#pragma unroll
    for (int t = 0; t < 3; t++)
      bfr[t] = *(const bf16x8*)&Bs[cur * 3840 + (WD + t * 16 + l15) * 40 + q * 8];
#pragma unroll
    for (int mt = 0; mt < 4; mt++)
#pragma unroll
      for (int nt = 0; nt < 3; nt++)
        acc[mt][nt] = __builtin_amdgcn_mfma_f32_16x16x32_bf16(af[mt], bfr[nt], acc[mt][nt], 0, 0, 0);
    if (have) K2_WRITEB(cur ^ 1);
    __syncthreads();
    cur ^= 1;
  }
#undef K2_STAGEA
#undef K2_LOADB
#undef K2_WRITEB

  // ---- fused contraction: part[f][c] = sum_{e, d in slice} G[e][d] * w2[c][e][d] ----
  __bf16* Gl = (__bf16*)smem2;             // [128][104] bf16 = 26624 B
  float pc[10];
#pragma unroll
  for (int c = 0; c < 10; c++) pc[c] = 0.0f;
  const int myhalf = WE >> 7;              // waves 0-3 -> half 0, waves 4-7 -> half 1
  const int eh = WE & 127;
  const int er = tid >> 2;                 // 0..127 e-row within half
  const int seg = tid & 3;                 // 24 d each

  for (int p = 0; p < 2; p++) {
    __syncthreads();
    if (myhalf == p) {
#pragma unroll
      for (int mt = 0; mt < 4; mt++)
#pragma unroll
        for (int nt = 0; nt < 3; nt++) {
          int row = eh + mt * 16 + q * 4;
          int col = WD + nt * 16 + l15;
#pragma unroll
          for (int r = 0; r < 4; r++)
            Gl[(row + r) * 104 + col] = (__bf16)acc[mt][nt][r];
        }
    }
    __syncthreads();
    int eglob = p * 128 + er;
    const __bf16* wbase = &w2[(size_t)eglob * D_ + dbase + seg * 24];
#pragma unroll
    for (int j = 0; j < 3; j++) {
      bf16x8 gv = *(const bf16x8*)&Gl[er * 104 + seg * 24 + j * 8];
      float g0 = (float)gv[0], g1 = (float)gv[1], g2 = (float)gv[2], g3 = (float)gv[3];
      float g4 = (float)gv[4], g5 = (float)gv[5], g6 = (float)gv[6], g7 = (float)gv[7];
#pragma unroll
      for (int c = 0; c < 10; c++) {
        bf16x8 wv = *(const bf16x8*)&wbase[(size_t)c * K3K_ + j * 8];
        pc[c] += g0 * (float)wv[0] + g1 * (float)wv[1] + g2 * (float)wv[2] + g3 * (float)wv[3]
               + g4 * (float)wv[4] + g5 * (float)wv[5] + g6 * (float)wv[6] + g7 * (float)wv[7];
      }
    }
  }
  // block reduction: 64-lane butterfly, then 8 waves -> 10 floats
#pragma unroll
  for (int c = 0; c < 10; c++)
#pragma unroll
    for (int off = 32; off >= 1; off >>= 1)
      pc[c] += __shfl_xor(pc[c], off, 64);
  __syncthreads();
  float* sp = (float*)smem2;
  if (lane == 0) {
#pragma unroll
    for (int c = 0; c < 10; c++) sp[wave * 10 + c] = pc[c];
  }
  __syncthreads();
  if (tid < 10) {
    float s = 0.0f;
#pragma unroll
    for (int w = 0; w < 8; w++) s += sp[w * 10 + tid];
    part[(size_t)f * 10 + tid] = s;
  }
}

// ---------------- K4: reduce 8 d-slice partials per b -> out ----------------
__global__ __launch_bounds__(640) void k4_final(const float* __restrict__ part,
                                                float* __restrict__ out) {
  int t = threadIdx.x;
  if (t < B_ * C_) {
    int b = t / C_, c = t - b * C_;
    float s = 0.0f;
#pragma unroll
    for (int g = 0; g < 8; g++)
      s += part[(size_t)(b * 8 + g) * C_ + c];
    out[t] = s * (1.0f / (196.0f * 256.0f));
  }
}

extern "C" void kernel_launch(void* const* d_in, const int* in_sizes, int n_in,
                              void* d_out, int out_size, void* d_ws, size_t ws_size,
                              hipStream_t stream) {
  const float* x    = (const float*)d_in[0];   // (64,196,768)
  const float* ag_w = (const float*)d_in[1];   // (256,768)
  const float* ag_b = (const float*)d_in[2];   // (256,)
  const float* lm_w = (const float*)d_in[3];   // (2560,768)
  float* out = (float*)d_out;                  // (64,10)

  char* ws = (char*)d_ws;
  const size_t W_BYTES  = (size_t)E_ * D_ * 2;
  const size_t ST_BYTES = (size_t)B_ * E_ * HWP_ * 2;
  const size_t W2_BYTES = (size_t)C_ * K3K_ * 2;
  __bf16* whi  = (__bf16*)(ws);
  __bf16* wlo  = (__bf16*)(ws + W_BYTES);
  __bf16* st   = (__bf16*)(ws + 2 * W_BYTES);
  __bf16* w2   = (__bf16*)(ws + 2 * W_BYTES + ST_BYTES);
  float*  part = (float*)(ws + 2 * W_BYTES + ST_BYTES + W2_BYTES);

  // 192 blocks ag_w + 1920 blocks w2 (10*K3K/4/256)
  k0_prep<<<dim3(192 + (C_ * K3K_) / 4 / 256), dim3(256), 0, stream>>>(ag_w, whi, wlo, lm_w, w2);
  k1_signs<<<dim3(MP_ / 64), dim3(256), 0, stream>>>(x, whi, wlo, ag_b, st);
  k2_fused<<<dim3(8 * B_), dim3(512), 0, stream>>>(st, x, w2, part);
  k4_final<<<dim3(1), dim3(640), 0, stream>>>(part, out);
}

// Round 12
// 143.102 us; speedup vs baseline: 1.1503x; 1.1503x over previous
//
#include <hip/hip_runtime.h>

#define B_    64
#define HW_   196
#define HWP_  224
#define D_    768
#define E_    256
#define C_    10
#define MP_   (B_*HWP_)   // 14336 padded rows
#define K3K_  (E_*D_)     // 196608 deep-K for final contraction
#define K3NB_ 256         // k3 blocks (768 k each = one e per block)

typedef _Float16 f16x8 __attribute__((ext_vector_type(8)));
typedef _Float16 f16x4 __attribute__((ext_vector_type(4)));
typedef __bf16 bf16x8 __attribute__((ext_vector_type(8)));
typedef __bf16 bf16x4 __attribute__((ext_vector_type(4)));
typedef __bf16 bf16x2 __attribute__((ext_vector_type(2)));
typedef float  f32x4  __attribute__((ext_vector_type(4)));

// async global->LDS, 16B per lane; LDS dest is wave-uniform base + lane*16
__device__ __forceinline__ void gld_lds16(const void* g, void* l) {
  __builtin_amdgcn_global_load_lds((const __attribute__((address_space(1))) void*)g,
                                   (__attribute__((address_space(3))) void*)l, 16, 0, 0);
}

// ---------------- K0prep: ag_w -> fp16 (single-term; k1 needs signs only) ----------
__global__ __launch_bounds__(256) void k0_prep(const float* __restrict__ w,
                                               _Float16* __restrict__ w16) {
  size_t i4 = ((size_t)blockIdx.x * 256 + threadIdx.x) * 4;
  float4 v = *(const float4*)&w[i4];
  f16x4 h;
  h[0] = (_Float16)v.x; h[1] = (_Float16)v.y;
  h[2] = (_Float16)v.z; h[3] = (_Float16)v.w;
  *(f16x4*)&w16[i4] = h;
}

// ---------------- K1: sign GEMM, SINGLE-TERM fp16 (3x fewer MFMA/LDS/L2) ----------
// Signs tolerate ~0.006 dot error (dot std ~27.7); fp16 single-term suffices.
// Structure = R8's depth-2 drain-free pipeline: B (w16) triple-buffered LDS DMA
// issued 2 steps ahead; A (fp32 x) reg-staged depth-2, cvt+ds_write after MFMA.
__global__ __launch_bounds__(256) void k1_signs(const float* __restrict__ x,
                                                const _Float16* __restrict__ w16,
                                                const float* __restrict__ bias,
                                                __bf16* __restrict__ st) {
  __shared__ __align__(16) char smem[59392];   // B 3x16KB = 48KB | A 2x5KB = 10KB
  const int m0 = blockIdx.x * 64;
  const int tid = threadIdx.x;
  const int wave = tid >> 6, lane = tid & 63;
  const int wn = wave * 64;                    // e-offset of this wave
  const int q = lane >> 4, l15 = lane & 15;
  const int swq = (q ^ ((l15 >> 1) & 3)) * 8;  // B read-side swizzled k-col

  const int ar = tid >> 2, ac = (tid & 3) * 8;
  const int am = m0 + ar;
  const int ab = am / HWP_;
  const int ahp = am - ab * HWP_;
  const bool avalid = (ahp < HW_);
  const float* aptr = &x[((size_t)ab * HW_ + (avalid ? ahp : 0)) * D_ + ac];

  const int swB = ((tid & 3) ^ ((tid >> 3) & 3)) * 8;   // source-side swizzle
  const size_t offB = (size_t)(tid >> 2) * D_ + swB;

  f32x4 acc[4][4] = {};
  float4 aX0, aX1, aY0, aY1;

#define K1_LOADA(r0, r1, kk) do { \
    r0 = *(const float4*)&aptr[(kk)]; \
    r1 = *(const float4*)&aptr[(kk) + 4]; \
  } while (0)

#define K1_CONV(bufA, r0, r1) do { \
    _Float16* AW = (_Float16*)(smem + 49152 + (bufA) * 5120); \
    float va[8] = {r0.x, r0.y, r0.z, r0.w, r1.x, r1.y, r1.z, r1.w}; \
    f16x8 hh; \
    _Pragma("unroll") \
    for (int j = 0; j < 8; j++) { \
      float vj = avalid ? va[j] : 0.0f; \
      hh[j] = (_Float16)vj; \
    } \
    *(f16x8*)&AW[ar * 40 + ac] = hh; \
  } while (0)

#define K1_DMAB(buf3, kk) do { \
    char* bb = smem + (buf3) * 16384; \
    _Pragma("unroll") \
    for (int c = 0; c < 4; c++) { \
      gld_lds16(&w16[offB + (size_t)c * 64 * D_ + (kk)], bb + c * 4096 + wave * 1024); \
    } \
  } while (0)

#define K1_COMPUTE(buf3, bufA) do { \
    const _Float16* BL = (const _Float16*)(smem + (buf3) * 16384); \
    const _Float16* AL = (const _Float16*)(smem + 49152 + (bufA) * 5120); \
    f16x8 ah[4], bh[4]; \
    _Pragma("unroll") \
    for (int t = 0; t < 4; t++) { \
      ah[t] = *(const f16x8*)&AL[(t * 16 + l15) * 40 + q * 8]; \
      bh[t] = *(const f16x8*)&BL[(wn + t * 16 + l15) * 32 + swq]; \
    } \
    __builtin_amdgcn_s_setprio(1); \
    _Pragma("unroll") \
    for (int mt = 0; mt < 4; mt++) \
      _Pragma("unroll") \
      for (int nt = 0; nt < 4; nt++) \
        acc[mt][nt] = __builtin_amdgcn_mfma_f32_16x16x32_f16(ah[mt], bh[nt], acc[mt][nt], 0, 0, 0); \
    __builtin_amdgcn_s_setprio(0); \
  } while (0)

#define K1_BAR() do { \
    asm volatile("s_waitcnt lgkmcnt(0)" ::: "memory"); \
    __builtin_amdgcn_s_barrier(); \
    __builtin_amdgcn_sched_barrier(0); \
  } while (0)

  K1_DMAB(0, 0);
  __builtin_amdgcn_sched_barrier(0);
  K1_LOADA(aX0, aX1, 0);
  __builtin_amdgcn_sched_barrier(0);
  K1_DMAB(1, 32);
  __builtin_amdgcn_sched_barrier(0);
  K1_LOADA(aY0, aY1, 32);
  K1_CONV(0, aX0, aX1);
  K1_BAR();

#pragma unroll
  for (int t = 0; t < 22; ++t) {
    K1_DMAB((t + 2) % 3, (t + 2) * 32);
    __builtin_amdgcn_sched_barrier(0);
    if ((t & 1) == 0) K1_LOADA(aX0, aX1, (t + 2) * 32);
    else              K1_LOADA(aY0, aY1, (t + 2) * 32);
    K1_COMPUTE(t % 3, t & 1);
    if ((t & 1) == 0) K1_CONV(1, aY0, aY1);
    else              K1_CONV(0, aX0, aX1);
    K1_BAR();
  }
  K1_COMPUTE(22 % 3, 0);
  K1_CONV(1, aY0, aY1);
  K1_BAR();
  K1_COMPUTE(23 % 3, 1);
  K1_BAR();

#undef K1_LOADA
#undef K1_CONV
#undef K1_DMAB
#undef K1_COMPUTE
#undef K1_BAR

  // ---- epilogue: sign+bias -> LDS transpose Sload[e][m] -> coalesced st writes ----
  __bf16* Sload = (__bf16*)smem;         // [256][72] = 36 KB (reuses pipeline pool)
#pragma unroll
  for (int mt = 0; mt < 4; mt++)
#pragma unroll
    for (int nt = 0; nt < 4; nt++) {
      int e = wn + nt * 16 + l15;
      float bv = bias[e];
      bf16x4 o;
#pragma unroll
      for (int r = 0; r < 4; r++) {
        int m = m0 + mt * 16 + q * 4 + r;
        int b = m / HWP_;
        int hp = m - b * HWP_;
        float v = acc[mt][nt][r] + bv;
        o[r] = (hp < HW_ && v > 0.0f) ? (__bf16)1.0f : (__bf16)0.0f;
      }
      *(bf16x4*)&Sload[e * 72 + mt * 16 + q * 4] = o;
    }
  __syncthreads();
#pragma unroll
  for (int it = 0; it < 16; it++) {
    int e = (tid >> 4) + it * 16;
    int m4 = (tid & 15) * 4;
    bf16x4 v = *(const bf16x4*)&Sload[e * 72 + m4];
    int mabs = m0 + m4;
    int b = mabs / HWP_;
    int hp = mabs - b * HWP_;
    *(bf16x4*)&st[((size_t)b * E_ + e) * HWP_ + hp] = v;
  }
}

// ---------------- K2: per-batch G = S^T · X, FULL-M (256 e), XCD-grouped ----------
__global__ __launch_bounds__(512) void k2_g(const __bf16* __restrict__ st,
                                            const float* __restrict__ x,
                                            __bf16* __restrict__ g) {
  __shared__ __align__(16) __bf16 As[2][256 * 32];   // 32 KB
  __shared__ __align__(16) __bf16 Bs[2][128 * 40];   // 20 KB, Bs[d][k] stride 40
  const int f = blockIdx.x;                // 0..383
  const int xcd = f & 7;
  const int slot = f >> 3;                 // 0..47
  const int b  = xcd + 8 * (slot / 6);
  const int d0 = (slot % 6) * 128;
  const int tid = threadIdx.x;
  const int wave = tid >> 6, lane = tid & 63;
  const int WE = (wave & 3) * 64;          // e-offset
  const int WD = (wave >> 2) * 64;         // d-offset within 128
  const int q = lane >> 4, l15 = lane & 15;
  const int ar = tid >> 2, ac = (tid & 3) * 8;
  const int ldA = wave * 512;
  const int dg = tid & 31, kp = tid >> 5;
  f32x4 acc[4][4] = {};

  const __bf16* gA = &st[((size_t)b * E_ + ar) * HWP_ + ac];
  const float4 zero4 = make_float4(0.f, 0.f, 0.f, 0.f);
  float4 f0, f1;

#define K2_STAGEA(buf, kk) do { \
    gld_lds16(gA + (kk),                       &As[buf][ldA]); \
    gld_lds16(gA + (size_t)128 * HWP_ + (kk),  &As[buf][4096 + ldA]); \
  } while (0)

#define K2_LOADB(kk) do { \
    int hp0 = (kk) + 2 * kp; \
    const float* bsrc = &x[((size_t)b * HW_ + hp0) * D_ + d0 + 4 * dg]; \
    f0 = (hp0     < HW_) ? *(const float4*)&bsrc[0]  : zero4; \
    f1 = (hp0 + 1 < HW_) ? *(const float4*)&bsrc[D_] : zero4; \
  } while (0)

#define K2_WRITEB(buf) do { \
    float rr0[4] = {f0.x, f0.y, f0.z, f0.w}; \
    float rr1[4] = {f1.x, f1.y, f1.z, f1.w}; \
    _Pragma("unroll") \
    for (int j = 0; j < 4; j++) { \
      bf16x2 o; \
      o[0] = (__bf16)rr0[j]; o[1] = (__bf16)rr1[j]; \
      *(bf16x2*)&Bs[buf][(4 * dg + j) * 40 + 2 * kp] = o; \
    } \
  } while (0)

  K2_STAGEA(0, 0);
  K2_LOADB(0);
  K2_WRITEB(0);
  __syncthreads();

  int cur = 0;
  for (int k0 = 0; k0 < HWP_; k0 += 32) {
    const bool have = (k0 + 32 < HWP_);
    if (have) {
      K2_STAGEA(cur ^ 1, k0 + 32);
      K2_LOADB(k0 + 32);
    }
    bf16x8 af[4], bfr[4];
#pragma unroll
    for (int t = 0; t < 4; t++) {
      af[t]  = *(const bf16x8*)&As[cur][(WE + t * 16 + l15) * 32 + q * 8];
      bfr[t] = *(const bf16x8*)&Bs[cur][(WD + t * 16 + l15) * 40 + q * 8];
    }
#pragma unroll
    for (int mt = 0; mt < 4; mt++)
#pragma unroll
      for (int nt = 0; nt < 4; nt++)
        acc[mt][nt] = __builtin_amdgcn_mfma_f32_16x16x32_bf16(af[mt], bfr[nt], acc[mt][nt], 0, 0, 0);
    if (have) K2_WRITEB(cur ^ 1);
    __syncthreads();
    cur ^= 1;
  }
#undef K2_STAGEA
#undef K2_LOADB
#undef K2_WRITEB

#pragma unroll
  for (int mt = 0; mt < 4; mt++)
#pragma unroll
    for (int nt = 0; nt < 4; nt++) {
      int d = d0 + WD + nt * 16 + l15;
#pragma unroll
      for (int r = 0; r < 4; r++) {
        int e = WE + mt * 16 + q * 4 + r;
        g[((size_t)b * E_ + e) * D_ + d] = (__bf16)acc[mt][nt][r];
      }
    }
}

// ---------------- K3: partials, lm_w converted ON THE FLY (R8 version) ----------
__global__ __launch_bounds__(256) void k3_mfma(const __bf16* __restrict__ g,
                                               const float* __restrict__ lmw,
                                               float* __restrict__ part) {
  __shared__ float sp[B_ * C_];
  const int tid = threadIdx.x;
  const int wave = tid >> 6, lane = tid & 63;
  const int q = lane >> 4, l15 = lane & 15;
  const int e = blockIdx.x;                 // 0..255
  f32x4 acc[4] = {};

  for (int i = tid; i < B_ * C_; i += 256) sp[i] = 0.0f;

#pragma unroll
  for (int ks = 0; ks < 6; ks++) {
    int d = wave * 192 + ks * 32 + q * 8;
    size_t k = (size_t)e * D_ + d;
    bf16x8 bfrag;
    if (l15 < C_) {
      const float* bp = &lmw[((size_t)e * C_ + l15) * D_ + d];
      float4 b0 = *(const float4*)&bp[0];
      float4 b1 = *(const float4*)&bp[4];
      float bb[8] = {b0.x, b0.y, b0.z, b0.w, b1.x, b1.y, b1.z, b1.w};
#pragma unroll
      for (int j = 0; j < 8; j++) bfrag[j] = (__bf16)bb[j];
    } else {
#pragma unroll
      for (int j = 0; j < 8; j++) bfrag[j] = (__bf16)0.0f;
    }
#pragma unroll
    for (int mt = 0; mt < 4; mt++) {
      bf16x8 afrag = *(const bf16x8*)&g[(size_t)(mt * 16 + l15) * K3K_ + k];
      acc[mt] = __builtin_amdgcn_mfma_f32_16x16x32_bf16(afrag, bfrag, acc[mt], 0, 0, 0);
    }
  }
  __syncthreads();
  if (l15 < C_) {
#pragma unroll
    for (int mt = 0; mt < 4; mt++)
#pragma unroll
      for (int r = 0; r < 4; r++) {
        int b = mt * 16 + q * 4 + r;
        atomicAdd(&sp[b * C_ + l15], acc[mt][r]);   // LDS atomics only
      }
  }
  __syncthreads();
  for (int i = tid; i < B_ * C_; i += 256)
    part[(size_t)blockIdx.x * (B_ * C_) + i] = sp[i];
}

// ---------------- K4: reduce 256 partials -> out ----------------
__global__ __launch_bounds__(256) void k4_reduce(const float* __restrict__ part,
                                                 float* __restrict__ out) {
  __shared__ float sp[256];
  const int b = blockIdx.x;
  const int tid = threadIdx.x;
  const int c = tid & 15, g16 = tid >> 4;   // 16 groups x 16 c-slots
  float s = 0.0f;
  if (c < C_) {
#pragma unroll
    for (int j = 0; j < 16; j++)
      s += part[(size_t)(g16 + 16 * j) * (B_ * C_) + b * C_ + c];
  }
  sp[tid] = s;
  __syncthreads();
  if (tid < C_) {
    float t = 0.0f;
#pragma unroll
    for (int j = 0; j < 16; j++) t += sp[j * 16 + tid];
    out[b * C_ + tid] = t * (1.0f / (196.0f * 256.0f));
  }
}

extern "C" void kernel_launch(void* const* d_in, const int* in_sizes, int n_in,
                              void* d_out, int out_size, void* d_ws, size_t ws_size,
                              hipStream_t stream) {
  const float* x    = (const float*)d_in[0];   // (64,196,768)
  const float* ag_w = (const float*)d_in[1];   // (256,768)
  const float* ag_b = (const float*)d_in[2];   // (256,)
  const float* lm_w = (const float*)d_in[3];   // (2560,768)
  float* out = (float*)d_out;                  // (64,10)

  char* ws = (char*)d_ws;
  const size_t W_BYTES  = (size_t)E_ * D_ * 2;
  const size_t ST_BYTES = (size_t)B_ * E_ * HWP_ * 2;
  const size_t G_BYTES  = (size_t)B_ * E_ * D_ * 2;
  _Float16* w16 = (_Float16*)(ws);
  __bf16* st    = (__bf16*)(ws + W_BYTES);
  __bf16* gb    = (__bf16*)(ws + W_BYTES + ST_BYTES);
  float*  part  = (float*)(ws + W_BYTES + ST_BYTES + G_BYTES);

  k0_prep<<<dim3((E_ * D_) / 4 / 256), dim3(256), 0, stream>>>(ag_w, w16);
  k1_signs<<<dim3(MP_ / 64), dim3(256), 0, stream>>>(x, w16, ag_b, st);
  k2_g<<<dim3(6 * B_), dim3(512), 0, stream>>>(st, x, gb);
  k3_mfma<<<dim3(K3NB_), dim3(256), 0, stream>>>(gb, lm_w, part);
  k4_reduce<<<dim3(B_), dim3(256), 0, stream>>>(part, out);
}